// Round 12
// baseline (101.237 us; speedup 1.0000x reference)
//
#include <hip/hip_runtime.h>
#include <hip/hip_bf16.h>

#define B_   16
#define NC_  1024
#define NQ_  128
#define D_   512
#define NKT  8        // K-tiles: 512/64

typedef __attribute__((ext_vector_type(8))) short bf16x8;
typedef __attribute__((ext_vector_type(4))) float f32x4;
typedef __attribute__((address_space(3))) char lds_char;
typedef const __attribute__((address_space(1))) char g_char;

// fp32 -> bf16 RTNE
__device__ __forceinline__ short f2bf(float x) {
    return __builtin_bit_cast(short, __float2bfloat16(x));
}

// Pre-kernel: qw[b][j][d] = bf16(q*w_cq + w_c); qterm[b][j] = q . w_q
__global__ __launch_bounds__(256) void prep_kernel(
    const float* __restrict__ q, const float* __restrict__ kern,
    short* __restrict__ qw, float* __restrict__ qterm)
{
    const int tid  = threadIdx.x;
    const int lane = tid & 63;
    const int row  = blockIdx.x * 4 + (tid >> 6);   // 0..2047 (b*128 + j)
    const int k0   = lane * 8;
    const float* qr = q + (size_t)row * D_;
    f32x4 a0 = *(const f32x4*)(qr + k0);
    f32x4 a1 = *(const f32x4*)(qr + k0 + 4);
    f32x4 g0 = *(const f32x4*)(kern + 2 * D_ + k0);      // w_cq
    f32x4 g1 = *(const f32x4*)(kern + 2 * D_ + k0 + 4);
    f32x4 w0 = *(const f32x4*)(kern + D_ + k0);          // w_q
    f32x4 w1 = *(const f32x4*)(kern + D_ + k0 + 4);
    f32x4 h0 = *(const f32x4*)(kern + k0);               // w_c
    f32x4 h1 = *(const f32x4*)(kern + k0 + 4);
    bf16x8 o;
    o[0] = f2bf(a0[0] * g0[0] + h0[0]); o[1] = f2bf(a0[1] * g0[1] + h0[1]);
    o[2] = f2bf(a0[2] * g0[2] + h0[2]); o[3] = f2bf(a0[3] * g0[3] + h0[3]);
    o[4] = f2bf(a1[0] * g1[0] + h1[0]); o[5] = f2bf(a1[1] * g1[1] + h1[1]);
    o[6] = f2bf(a1[2] * g1[2] + h1[2]); o[7] = f2bf(a1[3] * g1[3] + h1[3]);
    *(bf16x8*)(qw + (size_t)row * D_ + k0) = o;
    float s = a0[0]*w0[0] + a0[1]*w0[1] + a0[2]*w0[2] + a0[3]*w0[3]
            + a1[0]*w1[0] + a1[1]*w1[1] + a1[2]*w1[2] + a1[3]*w1[3];
    s += __shfl_xor(s, 1);  s += __shfl_xor(s, 2);  s += __shfl_xor(s, 4);
    s += __shfl_xor(s, 8);  s += __shfl_xor(s, 16); s += __shfl_xor(s, 32);
    if (lane == 0) qterm[row] = s;
}

// R12 PROBE: R11's sim structure, K-pipeline repeated REPS times (accumulate,
// scale by 1/REPS — exact for REPS=16). Purpose: (a) sim per-pass time =
// (dur_R12 - 19.2)/15; (b) force sim into rocprof top-5 for real counters
// (MfmaUtil / VALUBusy / LDS_BANK_CONFLICT / FETCH / VGPR / Occupancy).
template <int REPS>
__global__ __launch_bounds__(256, 3) void sim_kernel(
    const float* __restrict__ c, const short* __restrict__ qw,
    const float* __restrict__ qterm, const float* __restrict__ bias_p,
    float* __restrict__ out)
{
    __shared__ char lds[3][16384];   // per buf: A bf16 [64][64] (8KB) | B bf16 [64][64] (8KB)

    const int bid   = blockIdx.x;
    const int b     = ((bid & 7) << 1) | (bid >> 8);   // XCD-affine batch (bijective, 512 blocks)
    const int inner = (bid >> 3) & 31;
    const int mt    = inner >> 1;                      // 16 M-tiles of 64 rows
    const int nb    = inner & 1;                       // 2 N-halves of 64 cols
    const int tid   = threadIdx.x;
    const int lane  = tid & 63;
    const int w     = tid >> 6;
    const int wm    = w >> 1, wn = w & 1;              // 2x2 wave grid
    const int rif   = lane & 15;
    const int kg    = lane >> 4;

    // --- A reg-staging: thread t loads rows r0=t>>3, r1=r0+32; 8 floats at col (t&7)*8 ---
    const float* ag0 = c + (size_t)(b * NC_ + mt * 64 + (tid >> 3)) * D_ + (tid & 7) * 8;
    const float* ag1 = ag0 + (size_t)32 * D_;
    const int ar0 = tid >> 3, ar1 = ar0 + 32;
    const int aw0 = ar0 * 128 + (((tid & 7) * 16) ^ ((ar0 & 7) << 4));
    const int aw1 = ar1 * 128 + (((tid & 7) * 16) ^ ((ar1 & 7) << 4));

    // --- B staging via gload_lds: ch = w*2+l covers j-rows ch*8..+7 (128B rows) ---
    const char* bsrc[2]; int bdst[2];
    #pragma unroll
    for (int l = 0; l < 2; ++l) {
        int ch = w * 2 + l;
        int j  = ch * 8 + (lane >> 3);
        int so = ((lane & 7) * 16) ^ ((j & 7) << 4);
        bsrc[l] = (const char*)qw + ((size_t)(b * NQ_ + nb * 64 + j) * D_) * 2 + so;
        bdst[l] = 8192 + ch * 1024 + lane * 16;
    }

#define BSTAGE(BUF, KT)                                                           \
    do {                                                                          \
        lds_char* L_ = (lds_char*)&lds[(BUF)][0];                                 \
        __builtin_amdgcn_global_load_lds((g_char*)(bsrc[0] + (KT) * 128),         \
                                         (lds_char*)(L_ + bdst[0]), 16, 0, 0);    \
        __builtin_amdgcn_global_load_lds((g_char*)(bsrc[1] + (KT) * 128),         \
                                         (lds_char*)(L_ + bdst[1]), 16, 0, 0);    \
    } while (0)

#define ACVT(O0, O1, A00, A01, A10, A11)                                          \
    do {                                                                          \
        O0[0]=f2bf(A00[0]); O0[1]=f2bf(A00[1]); O0[2]=f2bf(A00[2]); O0[3]=f2bf(A00[3]); \
        O0[4]=f2bf(A01[0]); O0[5]=f2bf(A01[1]); O0[6]=f2bf(A01[2]); O0[7]=f2bf(A01[3]); \
        O1[0]=f2bf(A10[0]); O1[1]=f2bf(A10[1]); O1[2]=f2bf(A10[2]); O1[3]=f2bf(A10[3]); \
        O1[4]=f2bf(A11[0]); O1[5]=f2bf(A11[1]); O1[6]=f2bf(A11[2]); O1[7]=f2bf(A11[3]); \
    } while (0)

    f32x4 acc00 = {}, acc01 = {}, acc10 = {}, acc11 = {};

    #pragma unroll 1
    for (int rep = 0; rep < REPS; ++rep) {
        asm volatile("" ::: "memory");   // defeat cross-rep CSE/LICM of loads

        // Prologue: stage kt=0 into buf0
        {
            f32x4 a00 = *(const f32x4*)(ag0);
            f32x4 a01 = *(const f32x4*)(ag0 + 4);
            f32x4 a10 = *(const f32x4*)(ag1);
            f32x4 a11 = *(const f32x4*)(ag1 + 4);
            BSTAGE(0, 0);
            bf16x8 o0, o1;
            ACVT(o0, o1, a00, a01, a10, a11);
            *(bf16x8*)(&lds[0][aw0]) = o0;
            *(bf16x8*)(&lds[0][aw1]) = o1;
            __syncthreads();    // drains B gload_lds (vmcnt) + A ds_writes (lgkm)
        }

        #pragma unroll 1
        for (int kt = 0; kt < NKT; ++kt) {
            const bool st = (kt + 1 < NKT);
            f32x4 a00, a01, a10, a11;
            if (st) {   // issue kt+1 stage EARLY: A global loads + B gload_lds
                const float* g0 = ag0 + (kt + 1) * 64;
                const float* g1 = ag1 + (kt + 1) * 64;
                a00 = *(const f32x4*)(g0);
                a01 = *(const f32x4*)(g0 + 4);
                a10 = *(const f32x4*)(g1);
                a11 = *(const f32x4*)(g1 + 4);
                BSTAGE((kt + 1) % 3, kt + 1);
            }
            __builtin_amdgcn_sched_barrier(0);   // pin loads above compute

            const char* L = &lds[kt % 3][0];
            #pragma unroll
            for (int kk = 0; kk < 2; ++kk) {
                const int ks = kk * 64 + kg * 16;
                bf16x8 af0, af1, bf0, bf1;
                { int r = wm * 32 + rif;      af0 = *(const bf16x8*)(L + r * 128 + (ks ^ ((r & 7) << 4))); }
                { int r = wm * 32 + 16 + rif; af1 = *(const bf16x8*)(L + r * 128 + (ks ^ ((r & 7) << 4))); }
                { int j = wn * 32 + rif;      bf0 = *(const bf16x8*)(L + 8192 + j * 128 + (ks ^ ((j & 7) << 4))); }
                { int j = wn * 32 + 16 + rif; bf1 = *(const bf16x8*)(L + 8192 + j * 128 + (ks ^ ((j & 7) << 4))); }
                acc00 = __builtin_amdgcn_mfma_f32_16x16x32_bf16(af0, bf0, acc00, 0, 0, 0);
                acc01 = __builtin_amdgcn_mfma_f32_16x16x32_bf16(af0, bf1, acc01, 0, 0, 0);
                acc10 = __builtin_amdgcn_mfma_f32_16x16x32_bf16(af1, bf0, acc10, 0, 0, 0);
                acc11 = __builtin_amdgcn_mfma_f32_16x16x32_bf16(af1, bf1, acc11, 0, 0, 0);
            }

            if (st) {   // cvt + ds_write A(kt+1)
                char* Ln = &lds[(kt + 1) % 3][0];
                bf16x8 o0, o1;
                ACVT(o0, o1, a00, a01, a10, a11);
                *(bf16x8*)(Ln + aw0) = o0;
                *(bf16x8*)(Ln + aw1) = o1;
                __syncthreads();   // implicit vmcnt(0)+lgkm(0)
            }
        }
        __syncthreads();   // rep boundary: buf0 reuse safe
    }
#undef BSTAGE
#undef ACVT

    const float inv = 1.0f / (float)REPS;   // exact for REPS=16
    const float bias = *bias_p;
    const int colbase = nb * 64 + wn * 32;
    const float qt0 = qterm[b * NQ_ + colbase + rif]      + bias;
    const float qt1 = qterm[b * NQ_ + colbase + 16 + rif] + bias;
    #pragma unroll
    for (int mf = 0; mf < 2; ++mf) {
        float* o = out + ((size_t)(b * NC_ + mt * 64 + wm * 32 + mf * 16 + kg * 4)) * NQ_
                 + colbase + rif;
        const f32x4 a0 = mf ? acc10 : acc00;
        const f32x4 a1 = mf ? acc11 : acc01;
        #pragma unroll
        for (int r = 0; r < 4; ++r) {
            o[(size_t)r * NQ_ +  0] = a0[r] * inv + qt0;
            o[(size_t)r * NQ_ + 16] = a1[r] * inv + qt1;
        }
    }
}

extern "C" void kernel_launch(void* const* d_in, const int* in_sizes, int n_in,
                              void* d_out, int out_size, void* d_ws, size_t ws_size,
                              hipStream_t stream) {
    const float* c    = (const float*)d_in[0];
    const float* q    = (const float*)d_in[1];
    const float* kern = (const float*)d_in[2];
    const float* bias = (const float*)d_in[3];
    float* out = (float*)d_out;

    // ws layout: qw bf16 [2048][512] (2 MiB) | qterm f32 [2048]
    short* qw    = (short*)d_ws;
    float* qterm = (float*)((char*)d_ws + (size_t)2048 * 512 * 2);

    prep_kernel<<<512, 256, 0, stream>>>(q, kern, qw, qterm);
    sim_kernel<16><<<512, 256, 0, stream>>>(c, qw, qterm, bias, out);
}

// Round 13
// 16.356 us; speedup vs baseline: 6.1897x; 6.1897x over previous
//
#include <hip/hip_runtime.h>
#include <hip/hip_bf16.h>

#define B_   16
#define NC_  1024
#define NQ_  128
#define D_   512
#define NKT  8        // K-tiles: 512/64

typedef __attribute__((ext_vector_type(8))) short bf16x8;
typedef __attribute__((ext_vector_type(4))) float f32x4;

// fp32 -> bf16 RTNE
__device__ __forceinline__ short f2bf(float x) {
    return __builtin_bit_cast(short, __float2bfloat16(x));
}
// bf16 -> fp32 (exact)
__device__ __forceinline__ float bf2f(short s) {
    unsigned u = ((unsigned)(unsigned short)s) << 16;
    return __builtin_bit_cast(float, u);
}

// R13: SINGLE fused kernel (prep eliminated -> one launch).
//  out[b][i][j] = (A . B)_ij + ct_i + qt_j + bias, where
//  A = bf16(c * w_cq)  [w_cq folded into A at staging]
//  B = bf16(q)         [pure cast]
//  ct_i = c . w_c, qt_j = q . w_q  -> fp32 side-sums accumulated DURING staging.
// Geometry: R11-verified 64x64 tile, 4 waves 2Mx2N (wave 32x32), grid 512 (2/CU).
// Pipeline: reg-staged A+B, ISSUE(kt+2) at top of kt / WRITE(kt+1) after MFMA,
// ring-2 LDS, raw s_barrier + lgkmcnt(0) only (global loads in flight across
// barriers — no vmcnt drain). Full unroll -> static set/buf indices.
__global__ __launch_bounds__(256, 2) void sim_kernel(
    const float* __restrict__ c, const float* __restrict__ q,
    const float* __restrict__ kern, const float* __restrict__ bias_p,
    float* __restrict__ out)
{
    __shared__ __align__(16) char  lds[2][16384];  // per buf: A bf16[64][64] | B bf16[64][64]
    __shared__ __align__(16) short wl[1536];       // bf16: [0,512) w_c | [512,1024) w_q | [1024,1536) w_cq
    __shared__ __align__(16) float ctl[64];
    __shared__ __align__(16) float qtl[64];

    const int bid   = blockIdx.x;
    const int b     = ((bid & 7) << 1) | (bid >> 8);   // XCD-affine batch (bijective)
    const int inner = (bid >> 3) & 31;
    const int mt    = inner >> 1;                      // 16 M-tiles of 64 rows
    const int nb    = inner & 1;                       // 2 N-halves of 64 cols
    const int tid   = threadIdx.x;
    const int lane  = tid & 63;
    const int w     = tid >> 6;
    const int wm    = w >> 1, wn = w & 1;              // 2x2 wave grid
    const int rif   = lane & 15;
    const int kg    = lane >> 4;

    // ---- weights -> LDS bf16 (once; 192 threads x 8) ----
    if (tid < 192) {
        const float* s = kern + tid * 8;
        f32x4 v0 = *(const f32x4*)s;
        f32x4 v1 = *(const f32x4*)(s + 4);
        bf16x8 o;
        o[0]=f2bf(v0[0]); o[1]=f2bf(v0[1]); o[2]=f2bf(v0[2]); o[3]=f2bf(v0[3]);
        o[4]=f2bf(v1[0]); o[5]=f2bf(v1[1]); o[6]=f2bf(v1[2]); o[7]=f2bf(v1[3]);
        *(bf16x8*)&wl[tid * 8] = o;
    }

    // ---- A staging geometry: thread stages rows ar0, ar1=+32, col slice (tid&7)*8 per kt ----
    const int ar0 = tid >> 3, ar1 = ar0 + 32;
    const int acs = (tid & 7) * 8;                     // elem offset within 64-k window
    const float* ag0 = c + (size_t)(b * NC_ + mt * 64 + ar0) * D_ + acs;
    const float* ag1 = c + (size_t)(b * NC_ + mt * 64 + ar1) * D_ + acs;
    const int aw0 = ar0 * 128 + ((acs * 2)       ^ ((ar0 & 7) << 4));
    const int aw1 = ar1 * 128 + ((acs * 2)       ^ ((ar1 & 7) << 4));

    // ---- B staging geometry: thread stages row bj, col slice bp*16 per kt ----
    const int bj = tid >> 2, bp = tid & 3;
    const float* bg = q + (size_t)(b * NQ_ + nb * 64 + bj) * D_ + bp * 16;
    const int bw0 = 8192 + bj * 128 + ((bp * 32)      ^ ((bj & 7) << 4));
    const int bw1 = 8192 + bj * 128 + ((bp * 32 + 16) ^ ((bj & 7) << 4));

    f32x4 sa[2][4], sb[2][4];          // 2 tiles in flight (static idx after unroll)
    float ct0 = 0.f, ct1 = 0.f, qta = 0.f;
    f32x4 acc00 = {}, acc01 = {}, acc10 = {}, acc11 = {};

#define ISSUE(T)                                                   \
    do { const int s_ = (T) & 1;                                   \
        sa[s_][0] = *(const f32x4*)(ag0 + (T) * 64);               \
        sa[s_][1] = *(const f32x4*)(ag0 + (T) * 64 + 4);           \
        sa[s_][2] = *(const f32x4*)(ag1 + (T) * 64);               \
        sa[s_][3] = *(const f32x4*)(ag1 + (T) * 64 + 4);           \
        sb[s_][0] = *(const f32x4*)(bg + (T) * 64);                \
        sb[s_][1] = *(const f32x4*)(bg + (T) * 64 + 4);            \
        sb[s_][2] = *(const f32x4*)(bg + (T) * 64 + 8);            \
        sb[s_][3] = *(const f32x4*)(bg + (T) * 64 + 12);           \
    } while (0)

#define WRITE(T)                                                               \
    do { const int s_ = (T) & 1; char* Lw = &lds[s_][0];                       \
        bf16x8 wcq = *(const bf16x8*)&wl[1024 + (T) * 64 + acs];               \
        bf16x8 wc8 = *(const bf16x8*)&wl[       (T) * 64 + acs];               \
        bf16x8 wq0 = *(const bf16x8*)&wl[512  + (T) * 64 + bp * 16];           \
        bf16x8 wq1 = *(const bf16x8*)&wl[512  + (T) * 64 + bp * 16 + 8];       \
        bf16x8 oa0, oa1, ob0, ob1;                                             \
        _Pragma("unroll")                                                      \
        for (int e = 0; e < 8; ++e) {                                          \
            float wcqf = bf2f(wcq[e]);                                         \
            float x0 = sa[s_][e >> 2][e & 3];                                  \
            float x1 = sa[s_][2 + (e >> 2)][e & 3];                            \
            oa0[e] = f2bf(x0 * wcqf);                                          \
            oa1[e] = f2bf(x1 * wcqf);                                          \
            float wcf = bf2f(wc8[e]);                                          \
            ct0 += x0 * wcf;  ct1 += x1 * wcf;                                 \
            float y0 = sb[s_][e >> 2][e & 3];                                  \
            float y1 = sb[s_][2 + (e >> 2)][e & 3];                            \
            ob0[e] = f2bf(y0); ob1[e] = f2bf(y1);                              \
            qta += y0 * bf2f(wq0[e]) + y1 * bf2f(wq1[e]);                      \
        }                                                                      \
        *(bf16x8*)(Lw + aw0) = oa0;                                            \
        *(bf16x8*)(Lw + aw1) = oa1;                                            \
        *(bf16x8*)(Lw + bw0) = ob0;                                            \
        *(bf16x8*)(Lw + bw1) = ob1;                                            \
    } while (0)

#define COMPUTE(T)                                                                                   \
    do { const char* L = &lds[(T) & 1][0];                                                           \
        _Pragma("unroll")                                                                            \
        for (int kk = 0; kk < 2; ++kk) {                                                             \
            const int ks = kk * 64 + kg * 16;                                                        \
            bf16x8 af0, af1, bf0, bf1;                                                               \
            { int r = wm*32 + rif;      af0 = *(const bf16x8*)(L + r*128 + (ks ^ ((r & 7) << 4))); } \
            { int r = wm*32 + 16 + rif; af1 = *(const bf16x8*)(L + r*128 + (ks ^ ((r & 7) << 4))); } \
            { int j = wn*32 + rif;      bf0 = *(const bf16x8*)(L + 8192 + j*128 + (ks ^ ((j & 7) << 4))); } \
            { int j = wn*32 + 16 + rif; bf1 = *(const bf16x8*)(L + 8192 + j*128 + (ks ^ ((j & 7) << 4))); } \
            acc00 = __builtin_amdgcn_mfma_f32_16x16x32_bf16(af0, bf0, acc00, 0, 0, 0);               \
            acc01 = __builtin_amdgcn_mfma_f32_16x16x32_bf16(af0, bf1, acc01, 0, 0, 0);               \
            acc10 = __builtin_amdgcn_mfma_f32_16x16x32_bf16(af1, bf0, acc10, 0, 0, 0);               \
            acc11 = __builtin_amdgcn_mfma_f32_16x16x32_bf16(af1, bf1, acc11, 0, 0, 0);               \
        }                                                                                            \
    } while (0)

    // ---- prologue ----
    ISSUE(0); ISSUE(1);
    asm volatile("s_waitcnt lgkmcnt(0)" ::: "memory");   // weights ds_writes drained
    __builtin_amdgcn_sched_barrier(0);
    __builtin_amdgcn_s_barrier();                        // weights visible to all
    WRITE(0);                                            // stalls once on tile0 vmcnt
    asm volatile("s_waitcnt lgkmcnt(0)" ::: "memory");
    __builtin_amdgcn_sched_barrier(0);
    __builtin_amdgcn_s_barrier();                        // buf0 ready

    #pragma unroll
    for (int kt = 0; kt < NKT; ++kt) {
        if (kt + 2 < NKT) ISSUE(kt + 2);                 // loads 1 full iter ahead of use
        __builtin_amdgcn_sched_barrier(0);               // pin issue above compute
        COMPUTE(kt);
        if (kt + 1 < NKT) {
            WRITE(kt + 1);                               // consumes regs loaded last iter
            asm volatile("s_waitcnt lgkmcnt(0)" ::: "memory");  // ds ops only; vmcnt free
            __builtin_amdgcn_sched_barrier(0);
            __builtin_amdgcn_s_barrier();
        }
    }
#undef ISSUE
#undef WRITE
#undef COMPUTE

    // ---- side-term reductions ----
    ct0 += __shfl_xor(ct0, 1); ct0 += __shfl_xor(ct0, 2); ct0 += __shfl_xor(ct0, 4);
    ct1 += __shfl_xor(ct1, 1); ct1 += __shfl_xor(ct1, 2); ct1 += __shfl_xor(ct1, 4);
    qta += __shfl_xor(qta, 1); qta += __shfl_xor(qta, 2);
    if ((tid & 7) == 0) { ctl[ar0] = ct0; ctl[ar1] = ct1; }
    if ((tid & 3) == 0) qtl[bj] = qta;
    asm volatile("s_waitcnt lgkmcnt(0)" ::: "memory");
    __builtin_amdgcn_sched_barrier(0);
    __builtin_amdgcn_s_barrier();

    // ---- epilogue ----
    const float bias = *bias_p;
    const int jc = wn * 32;
    const float qt0 = qtl[jc + rif]      + bias;
    const float qt1 = qtl[jc + 16 + rif] + bias;
    #pragma unroll
    for (int mf = 0; mf < 2; ++mf) {
        f32x4 ctv = *(const f32x4*)&ctl[wm * 32 + mf * 16 + kg * 4];
        float* o = out + ((size_t)(b * NC_ + mt * 64 + wm * 32 + mf * 16 + kg * 4)) * NQ_
                 + nb * 64 + jc + rif;
        const f32x4 a0 = mf ? acc10 : acc00;
        const f32x4 a1 = mf ? acc11 : acc01;
        #pragma unroll
        for (int r = 0; r < 4; ++r) {
            o[(size_t)r * NQ_ +  0] = a0[r] + ctv[r] + qt0;
            o[(size_t)r * NQ_ + 16] = a1[r] + ctv[r] + qt1;
        }
    }
}

extern "C" void kernel_launch(void* const* d_in, const int* in_sizes, int n_in,
                              void* d_out, int out_size, void* d_ws, size_t ws_size,
                              hipStream_t stream) {
    const float* c    = (const float*)d_in[0];
    const float* q    = (const float*)d_in[1];
    const float* kern = (const float*)d_in[2];
    const float* bias = (const float*)d_in[3];
    float* out = (float*)d_out;

    // Single fused launch: 16 b x 16 mt x 2 nb = 512 blocks (XCD-affine decode in-kernel).
    sim_kernel<<<512, 256, 0, stream>>>(c, q, kern, bias, out);
}